// Round 1
// baseline (501.104 us; speedup 1.0000x reference)
//
#include <hip/hip_runtime.h>

// ---------------- workspace layout (float offsets) ----------------
// xpn:  0        .. 524288     [2][256][1024] normalized xp
// xqn:  524288   .. 1048576
// aff:  1048576  .. 3145728    [2][1024 p][1024 q]
// xc:   3145728  .. 5242880    [2][1024 p][1024 q]
// Ktab: 5242880  .. 5293505    [81 classes][625 taps]
// bias: 5293505  .. 5294369    [32 l][3 cd][3 ch][3 cw]
// part: 5294592  .. 5343744    topq partials [2][8][3][1024]
// total ~21.4 MB

#define AFF_H 12
#define AFF_W 38

static __device__ __forceinline__ int imax(int a, int b){ return a > b ? a : b; }
static __device__ __forceinline__ int imin(int a, int b){ return a < b ? a : b; }

static __device__ __forceinline__ void ins3(float& a0, float& a1, float& a2, float v){
  if (v > a0){ a2 = a1; a1 = a0; a0 = v; }
  else if (v > a1){ a2 = a1; a1 = v; }
  else if (v > a2){ a2 = v; }
}

// ---------------- L2-normalize xp, xq over channel dim ----------------
__global__ __launch_bounds__(256) void nrm_k(const float* __restrict__ xp,
                                             const float* __restrict__ xq,
                                             float* __restrict__ ws){
  int bid = blockIdx.x;                       // 64 blocks: which(2) x b(2) x pg(16)
  int pg = bid & 15, b = (bid >> 4) & 1, which = bid >> 5;
  const float* src = which ? xq : xp;
  float* dst = ws + (which ? 524288u : 0u);
  int t = threadIdx.x, lane = t & 63, wv = t >> 6;
  int p = pg * 64 + lane;
  const float* s0 = src + (size_t)b * 262144 + p;
  float* d0 = dst + (size_t)b * 262144 + p;
  float s = 0.f;
  for (int c = wv * 64; c < wv * 64 + 64; ++c){
    float v = s0[(size_t)c * 1024]; s += v * v;
  }
  __shared__ float red[4][64];
  __shared__ float invn[64];
  red[wv][lane] = s;
  __syncthreads();
  if (wv == 0){
    float tot = red[0][lane] + red[1][lane] + red[2][lane] + red[3][lane];
    invn[lane] = 1.0f / fmaxf(sqrtf(tot), 1e-12f);
  }
  __syncthreads();
  float inv = invn[lane];
  for (int c = wv * 64; c < wv * 64 + 64; ++c){
    d0[(size_t)c * 1024] = s0[(size_t)c * 1024] * inv;
  }
}

// ---------------- precompute 81 class kernels + bias table ----------------
// class per dim: 0 (coord==0: conv2 tap q2=0 masked), 1 interior, 2 (coord==31: q2=2 masked)
__global__ __launch_bounds__(256) void tab_k(const float* __restrict__ W1,
                                             const float* __restrict__ B1,
                                             const float* __restrict__ W2,
                                             const float* __restrict__ B2,
                                             float* __restrict__ ws){
  __shared__ float sW1[1296], sW2[1296];
  for (int i = threadIdx.x; i < 1296; i += 256){ sW1[i] = W1[i]; sW2[i] = W2[i]; }
  __syncthreads();
  int tid = blockIdx.x * 256 + threadIdx.x;
  if (tid < 50625){
    int c = tid / 625, r = tid % 625;
    int cw = c % 3, ch = (c / 3) % 3, cd = (c / 9) % 3, cl = c / 27;
    int rw = r % 5, rh = (r / 5) % 5, rd = (r / 25) % 5, rl = r / 125;
    int al0 = imax(0, rl - 2), al1 = imin(2, rl);
    if (cl == 0) al0 = imax(al0, 1);
    if (cl == 2) al1 = imin(al1, 1);
    int ad0 = imax(0, rd - 2), ad1 = imin(2, rd);
    if (cd == 0) ad0 = imax(ad0, 1);
    if (cd == 2) ad1 = imin(ad1, 1);
    int ah0 = imax(0, rh - 2), ah1 = imin(2, rh);
    if (ch == 0) ah0 = imax(ah0, 1);
    if (ch == 2) ah1 = imin(ah1, 1);
    int aw0 = imax(0, rw - 2), aw1 = imin(2, rw);
    if (cw == 0) aw0 = imax(aw0, 1);
    if (cw == 2) aw1 = imin(aw1, 1);
    float s = 0.f;
    for (int a = al0; a <= al1; ++a)
      for (int bq = ad0; bq <= ad1; ++bq)
        for (int cq = ah0; cq <= ah1; ++cq)
          for (int dq = aw0; dq <= aw1; ++dq){
            int q2 = ((a * 3 + bq) * 3 + cq) * 3 + dq;
            int q1 = (((rl - a) * 3 + (rd - bq)) * 3 + (rh - cq)) * 3 + (rw - dq);
            for (int co = 0; co < 16; ++co)
              s += sW2[co * 81 + q2] * sW1[co * 81 + q1];
          }
    ws[5242880u + tid] = s;
  } else if (tid < 50625 + 864){
    int t2 = tid - 50625;
    int l = t2 / 27, rest = t2 % 27;
    int cd = rest / 9, ch = (rest / 3) % 3, cw = rest % 3;
    float v = 0.f;
    for (int i = 0; i < 3; ++i){ int y = l + i - 1; if (y >= 0 && y < 32) v += B2[i]; }
    int jlo = (cd == 0) ? 1 : 0, jhi = (cd == 2) ? 1 : 2;
    int klo = (ch == 0) ? 1 : 0, khi = (ch == 2) ? 1 : 2;
    int mlo = (cw == 0) ? 1 : 0, mhi = (cw == 2) ? 1 : 2;
    for (int i = 0; i < 3; ++i){
      int y = l + i - 1; if (y < 0 || y >= 32) continue;
      for (int co = 0; co < 16; ++co){
        float b1e = 0.f;
        for (int i2 = 0; i2 < 3; ++i2){
          int y2 = y + i2 - 1; if (y2 >= 0 && y2 < 32) b1e += B1[i2 * 16 + co];
        }
        float S = 0.f;
        for (int j = jlo; j <= jhi; ++j)
          for (int k = klo; k <= khi; ++k)
            for (int m = mlo; m <= mhi; ++m)
              S += sW2[co * 81 + ((i * 3 + j) * 3 + k) * 3 + m];
        v += b1e * S;
      }
    }
    ws[5293505u + t2] = v;
  }
}

// ---------------- aff = xpn^T * xqn  (per batch 1024x1024, K=256) ----------------
__global__ __launch_bounds__(256) void gemm_k(float* __restrict__ ws){
  int bid = blockIdx.x;                       // 512: b(2) x pi(16) x qi(16)
  int qi = bid & 15, pi = (bid >> 4) & 15, b = bid >> 8;
  const float* A = ws + (size_t)b * 262144;             // xpn [c][p]
  const float* B = ws + 524288u + (size_t)b * 262144;   // xqn [c][q]
  float* C = ws + 1048576u + (size_t)b * 1048576;       // aff [p][q]
  int t = threadIdx.x, tx = t & 15, ty = t >> 4;
  int lp = t & 63, lr = t >> 6;
  __shared__ float As[16][64], Bs[16][64];
  float acc[4][4] = {};
  for (int k0 = 0; k0 < 256; k0 += 16){
    __syncthreads();
    #pragma unroll
    for (int j = 0; j < 4; ++j){
      int kk = lr + j * 4;
      As[kk][lp] = A[(size_t)(k0 + kk) * 1024 + pi * 64 + lp];
      Bs[kk][lp] = B[(size_t)(k0 + kk) * 1024 + qi * 64 + lp];
    }
    __syncthreads();
    #pragma unroll
    for (int kk = 0; kk < 16; ++kk){
      float av[4], bv[4];
      #pragma unroll
      for (int i = 0; i < 4; ++i){ av[i] = As[kk][ty * 4 + i]; bv[i] = Bs[kk][tx * 4 + i]; }
      #pragma unroll
      for (int i = 0; i < 4; ++i)
        #pragma unroll
        for (int j = 0; j < 4; ++j)
          acc[i][j] = fmaf(av[i], bv[j], acc[i][j]);
    }
  }
  #pragma unroll
  for (int i = 0; i < 4; ++i){
    float4 v = make_float4(acc[i][0], acc[i][1], acc[i][2], acc[i][3]);
    *(float4*)&C[(size_t)(pi * 64 + ty * 4 + i) * 1024 + qi * 64 + tx * 4] = v;
  }
}

// ---------------- composed 5^4 conv + bias; block = (b, l0, d0, h-strip of 8) ----------------
__global__ __launch_bounds__(256) void conv_k(float* __restrict__ ws){
  __shared__ float saff[5 * 5 * AFF_H * AFF_W];  // 11400 f = 45.6 KB (reused for reduction)
  __shared__ float sK[625];
  int bid0 = blockIdx.x;
  int bid = (bid0 & 7) * 1024 + (bid0 >> 3);     // XCD swizzle (8192 % 8 == 0, bijective)
  int hq = bid & 3, d0 = (bid >> 2) & 31, l0 = (bid >> 7) & 31, b = bid >> 12;
  int h0 = hq * 8;
  int t = threadIdx.x;
  const float* aff = ws + 1048576u + (size_t)b * 1048576;
  float* xc = ws + 3145728u + (size_t)b * 1048576;
  const float* Ktab = ws + 5242880u;
  const float* bias = ws + 5293505u;
  int cl = (l0 == 0) ? 0 : (l0 == 31) ? 2 : 1;
  int cd = (d0 == 0) ? 0 : (d0 == 31) ? 2 : 1;
  int cmain = ((cl * 3 + cd) * 3 + 1) * 3 + 1;
  for (int i = t; i < 625; i += 256) sK[i] = Ktab[cmain * 625 + i];
  // stage aff tile: l' in l0-2..l0+2, d' in d0-2..d0+2, h' in h0-2..h0+9, w' in -2..35 (zero pad)
  for (int idx = t; idx < 5 * 5 * AFF_H * AFF_W; idx += 256){
    int wi = idx % AFF_W;
    int row = idx / AFF_W;
    int hi = row % AFF_H;
    int r2 = row / AFF_H;
    int dd = r2 % 5, dl = r2 / 5;
    int lp = l0 + dl - 2, dp = d0 + dd - 2, hp = h0 + hi - 2, wp = wi - 2;
    float v = 0.f;
    if (lp >= 0 && lp < 32 && dp >= 0 && dp < 32 && hp >= 0 && hp < 32 && wp >= 0 && wp < 32)
      v = aff[(size_t)(lp * 32 + dp) * 1024 + hp * 32 + wp];
    saff[idx] = v;
  }
  __syncthreads();
  // main pass: 32 units (8 h x 4 w-octets), 8 thread-groups split the 25 (dl,dd) planes
  int u = t & 31, g = t >> 5;
  int hh = u >> 2, oct = u & 3, w0 = oct * 8;
  float acc[8] = {};
  for (int idx = g; idx < 25; idx += 8){
    float kv[25];
    #pragma unroll
    for (int i = 0; i < 25; ++i) kv[i] = sK[idx * 25 + i];
    #pragma unroll
    for (int dh = 0; dh < 5; ++dh){
      const float* rowp = &saff[(idx * AFF_H + hh + dh) * AFF_W + w0];
      float f[12];
      #pragma unroll
      for (int i = 0; i < 6; ++i){
        float2 v2 = *(const float2*)&rowp[i * 2];
        f[2 * i] = v2.x; f[2 * i + 1] = v2.y;
      }
      #pragma unroll
      for (int dw = 0; dw < 5; ++dw){
        float kf = kv[dh * 5 + dw];
        #pragma unroll
        for (int j = 0; j < 8; ++j)
          acc[j] = fmaf(kf, f[j + dw], acc[j]);
      }
    }
  }
  // shell pass: h/w-boundary outputs recomputed with their exact class kernel
  int hs = -1, wsx = 0;
  if (h0 == 0){
    if (t < 32){ hs = 0; wsx = t; }
    else if (t < 46){ int j = t - 32; hs = 1 + (j >> 1); wsx = (j & 1) ? 31 : 0; }
  } else if (h0 == 24){
    if (t < 32){ hs = 31; wsx = t; }
    else if (t < 46){ int j = t - 32; hs = 24 + (j >> 1); wsx = (j & 1) ? 31 : 0; }
  } else {
    if (t < 16){ hs = h0 + (t >> 1); wsx = (t & 1) ? 31 : 0; }
  }
  if (hs >= 0){
    int chh = (hs == 0) ? 0 : (hs == 31) ? 2 : 1;
    int cww = (wsx == 0) ? 0 : (wsx == 31) ? 2 : 1;
    int cls = ((cl * 3 + cd) * 3 + chh) * 3 + cww;
    const float* kr = Ktab + cls * 625;
    float s = 0.f;
    for (int rl = 0; rl < 5; ++rl)
      for (int rd = 0; rd < 5; ++rd){
        const float* base = &saff[((rl * 5 + rd) * AFF_H + (hs - h0)) * AFF_W + wsx];
        const float* kp = &kr[(rl * 5 + rd) * 25];
        #pragma unroll
        for (int rh = 0; rh < 5; ++rh)
          #pragma unroll
          for (int rw = 0; rw < 5; ++rw)
            s = fmaf(kp[rh * 5 + rw], base[rh * AFF_W + rw], s);
      }
    s += bias[l0 * 27 + cd * 9 + chh * 3 + cww];
    xc[(size_t)(l0 * 32 + d0) * 1024 + hs * 32 + wsx] = s;
  }
  __syncthreads();
  // reduce the 8 partial groups (overlay into saff), add bias, write interior
  #pragma unroll
  for (int j = 0; j < 8; ++j) saff[(g * 32 + u) * 8 + j] = acc[j];
  __syncthreads();
  {
    int u2 = t >> 3, j = t & 7;
    float s = 0.f;
    #pragma unroll
    for (int gg = 0; gg < 8; ++gg) s += saff[(gg * 32 + u2) * 8 + j];
    int h = h0 + (u2 >> 2);
    int w = (u2 & 3) * 8 + j;
    if (!(h == 0 || h == 31 || w == 0 || w == 31)){
      s += bias[l0 * 27 + cd * 9 + 4];   // interior h,w class (1,1)
      xc[(size_t)(l0 * 32 + d0) * 1024 + h * 32 + w] = s;
    }
  }
}

// ---------------- valp: top3 over q for each (b,p); wave per row ----------------
__global__ __launch_bounds__(256) void topp_k(const float* __restrict__ ws, float* __restrict__ out){
  const float* xc = ws + 3145728u;
  int wid = blockIdx.x * 4 + (threadIdx.x >> 6);
  int lane = threadIdx.x & 63;
  int b = wid >> 10, p = wid & 1023;
  const float* row = xc + (size_t)b * 1048576 + (size_t)p * 1024;
  float a0 = -3.4e38f, a1 = a0, a2 = a0;
  #pragma unroll 4
  for (int j = 0; j < 16; ++j) ins3(a0, a1, a2, row[lane + j * 64]);
  for (int off = 32; off; off >>= 1){
    float b0 = __shfl_xor(a0, off), b1 = __shfl_xor(a1, off), b2 = __shfl_xor(a2, off);
    ins3(a0, a1, a2, b0); ins3(a0, a1, a2, b1); ins3(a0, a1, a2, b2);
  }
  if (lane < 3){
    float v = (lane == 0) ? a0 : (lane == 1) ? a1 : a2;
    out[b * 3072 + lane * 1024 + p] = v;
  }
}

// ---------------- valq: top3 over p for each (b,q); 2-stage coalesced ----------------
__global__ __launch_bounds__(256) void topq1_k(float* __restrict__ ws){
  const float* xc = ws + 3145728u;
  float* part = ws + 5294592u;
  int bid = blockIdx.x;                       // 64: b(2) x pc(8) x qq(4)
  int qq = bid & 3, pc = (bid >> 2) & 7, b = bid >> 5;
  int q = qq * 256 + threadIdx.x;
  const float* base = xc + (size_t)b * 1048576 + q;
  float a0 = -3.4e38f, a1 = a0, a2 = a0;
  #pragma unroll 4
  for (int i = 0; i < 128; ++i) ins3(a0, a1, a2, base[(size_t)(pc * 128 + i) * 1024]);
  part[(size_t)((b * 8 + pc) * 3 + 0) * 1024 + q] = a0;
  part[(size_t)((b * 8 + pc) * 3 + 1) * 1024 + q] = a1;
  part[(size_t)((b * 8 + pc) * 3 + 2) * 1024 + q] = a2;
}

__global__ __launch_bounds__(256) void topq2_k(const float* __restrict__ ws, float* __restrict__ out){
  const float* part = ws + 5294592u;
  int gid = blockIdx.x * 256 + threadIdx.x;   // 2048
  int b = gid >> 10, q = gid & 1023;
  float a0 = -3.4e38f, a1 = a0, a2 = a0;
  #pragma unroll
  for (int c = 0; c < 24; ++c) ins3(a0, a1, a2, part[(size_t)(b * 24 + c) * 1024 + q]);
  out[6144 + b * 3072 + q] = a0;
  out[6144 + b * 3072 + 1024 + q] = a1;
  out[6144 + b * 3072 + 2048 + q] = a2;
}

extern "C" void kernel_launch(void* const* d_in, const int* in_sizes, int n_in,
                              void* d_out, int out_size, void* d_ws, size_t ws_size,
                              hipStream_t stream){
  const float* xp = (const float*)d_in[0];
  const float* xq = (const float*)d_in[1];
  const float* W1 = (const float*)d_in[2];
  const float* B1 = (const float*)d_in[3];
  const float* W2 = (const float*)d_in[4];
  const float* B2 = (const float*)d_in[5];
  float* out = (float*)d_out;
  float* ws = (float*)d_ws;
  hipLaunchKernelGGL(nrm_k,   dim3(64),   dim3(256), 0, stream, xp, xq, ws);
  hipLaunchKernelGGL(tab_k,   dim3(202),  dim3(256), 0, stream, W1, B1, W2, B2, ws);
  hipLaunchKernelGGL(gemm_k,  dim3(512),  dim3(256), 0, stream, ws);
  hipLaunchKernelGGL(conv_k,  dim3(8192), dim3(256), 0, stream, ws);
  hipLaunchKernelGGL(topp_k,  dim3(512),  dim3(256), 0, stream, ws, out);
  hipLaunchKernelGGL(topq1_k, dim3(64),   dim3(256), 0, stream, ws);
  hipLaunchKernelGGL(topq2_k, dim3(8),    dim3(256), 0, stream, ws, out);
}

// Round 2
// 388.708 us; speedup vs baseline: 1.2892x; 1.2892x over previous
//
#include <hip/hip_runtime.h>

// ---------------- workspace layout (float offsets) ----------------
// xpn:  0        .. 524288     [2][256][1024] normalized xp
// xqn:  524288   .. 1048576
// aff:  1048576  .. 3145728    [2][1024 p][1024 q]
// xc:   3145728  .. 5242880    [2][1024 p][1024 q]
// Ktab: 5242880  .. 5293505    [81 classes][625 taps]
// bias: 5293505  .. 5294369    [32 l][3 cd][3 ch][3 cw]
// part: 5294592  .. 5343744    topq partials [2][8][3][1024]
// total ~21.4 MB

#define AFF_H 12
#define AFF_W 38

static __device__ __forceinline__ int imax(int a, int b){ return a > b ? a : b; }
static __device__ __forceinline__ int imin(int a, int b){ return a < b ? a : b; }

static __device__ __forceinline__ void ins3(float& a0, float& a1, float& a2, float v){
  if (v > a0){ a2 = a1; a1 = a0; a0 = v; }
  else if (v > a1){ a2 = a1; a1 = v; }
  else if (v > a2){ a2 = v; }
}

// ---------------- L2-normalize xp, xq over channel dim ----------------
__global__ __launch_bounds__(256) void nrm_k(const float* __restrict__ xp,
                                             const float* __restrict__ xq,
                                             float* __restrict__ ws){
  int bid = blockIdx.x;                       // 64 blocks: which(2) x b(2) x pg(16)
  int pg = bid & 15, b = (bid >> 4) & 1, which = bid >> 5;
  const float* src = which ? xq : xp;
  float* dst = ws + (which ? 524288u : 0u);
  int t = threadIdx.x, lane = t & 63, wv = t >> 6;
  int p = pg * 64 + lane;
  const float* s0 = src + (size_t)b * 262144 + p;
  float* d0 = dst + (size_t)b * 262144 + p;
  float s = 0.f;
  for (int c = wv * 64; c < wv * 64 + 64; ++c){
    float v = s0[(size_t)c * 1024]; s += v * v;
  }
  __shared__ float red[4][64];
  __shared__ float invn[64];
  red[wv][lane] = s;
  __syncthreads();
  if (wv == 0){
    float tot = red[0][lane] + red[1][lane] + red[2][lane] + red[3][lane];
    invn[lane] = 1.0f / fmaxf(sqrtf(tot), 1e-12f);
  }
  __syncthreads();
  float inv = invn[lane];
  for (int c = wv * 64; c < wv * 64 + 64; ++c){
    d0[(size_t)c * 1024] = s0[(size_t)c * 1024] * inv;
  }
}

// ---------------- precompute 81 class kernels + bias table ----------------
// class per dim: 0 (coord==0: conv2 tap q2=0 masked), 1 interior, 2 (coord==31: q2=2 masked)
__global__ __launch_bounds__(256) void tab_k(const float* __restrict__ W1,
                                             const float* __restrict__ B1,
                                             const float* __restrict__ W2,
                                             const float* __restrict__ B2,
                                             float* __restrict__ ws){
  __shared__ float sW1[1296], sW2[1296];
  for (int i = threadIdx.x; i < 1296; i += 256){ sW1[i] = W1[i]; sW2[i] = W2[i]; }
  __syncthreads();
  int tid = blockIdx.x * 256 + threadIdx.x;
  if (tid < 50625){
    int c = tid / 625, r = tid % 625;
    int cw = c % 3, ch = (c / 3) % 3, cd = (c / 9) % 3, cl = c / 27;
    int rw = r % 5, rh = (r / 5) % 5, rd = (r / 25) % 5, rl = r / 125;
    int al0 = imax(0, rl - 2), al1 = imin(2, rl);
    if (cl == 0) al0 = imax(al0, 1);
    if (cl == 2) al1 = imin(al1, 1);
    int ad0 = imax(0, rd - 2), ad1 = imin(2, rd);
    if (cd == 0) ad0 = imax(ad0, 1);
    if (cd == 2) ad1 = imin(ad1, 1);
    int ah0 = imax(0, rh - 2), ah1 = imin(2, rh);
    if (ch == 0) ah0 = imax(ah0, 1);
    if (ch == 2) ah1 = imin(ah1, 1);
    int aw0 = imax(0, rw - 2), aw1 = imin(2, rw);
    if (cw == 0) aw0 = imax(aw0, 1);
    if (cw == 2) aw1 = imin(aw1, 1);
    float s = 0.f;
    for (int a = al0; a <= al1; ++a)
      for (int bq = ad0; bq <= ad1; ++bq)
        for (int cq = ah0; cq <= ah1; ++cq)
          for (int dq = aw0; dq <= aw1; ++dq){
            int q2 = ((a * 3 + bq) * 3 + cq) * 3 + dq;
            int q1 = (((rl - a) * 3 + (rd - bq)) * 3 + (rh - cq)) * 3 + (rw - dq);
            for (int co = 0; co < 16; ++co)
              s += sW2[co * 81 + q2] * sW1[co * 81 + q1];
          }
    ws[5242880u + tid] = s;
  } else if (tid < 50625 + 864){
    int t2 = tid - 50625;
    int l = t2 / 27, rest = t2 % 27;
    int cd = rest / 9, ch = (rest / 3) % 3, cw = rest % 3;
    float v = 0.f;
    for (int i = 0; i < 3; ++i){ int y = l + i - 1; if (y >= 0 && y < 32) v += B2[i]; }
    int jlo = (cd == 0) ? 1 : 0, jhi = (cd == 2) ? 1 : 2;
    int klo = (ch == 0) ? 1 : 0, khi = (ch == 2) ? 1 : 2;
    int mlo = (cw == 0) ? 1 : 0, mhi = (cw == 2) ? 1 : 2;
    for (int i = 0; i < 3; ++i){
      int y = l + i - 1; if (y < 0 || y >= 32) continue;
      for (int co = 0; co < 16; ++co){
        float b1e = 0.f;
        for (int i2 = 0; i2 < 3; ++i2){
          int y2 = y + i2 - 1; if (y2 >= 0 && y2 < 32) b1e += B1[i2 * 16 + co];
        }
        float S = 0.f;
        for (int j = jlo; j <= jhi; ++j)
          for (int k = klo; k <= khi; ++k)
            for (int m = mlo; m <= mhi; ++m)
              S += sW2[co * 81 + ((i * 3 + j) * 3 + k) * 3 + m];
        v += b1e * S;
      }
    }
    ws[5293505u + t2] = v;
  }
}

// ---------------- aff = xpn^T * xqn  (per batch 1024x1024, K=256) ----------------
__global__ __launch_bounds__(256) void gemm_k(float* __restrict__ ws){
  int bid = blockIdx.x;                       // 512: b(2) x pi(16) x qi(16)
  int qi = bid & 15, pi = (bid >> 4) & 15, b = bid >> 8;
  const float* A = ws + (size_t)b * 262144;             // xpn [c][p]
  const float* B = ws + 524288u + (size_t)b * 262144;   // xqn [c][q]
  float* C = ws + 1048576u + (size_t)b * 1048576;       // aff [p][q]
  int t = threadIdx.x, tx = t & 15, ty = t >> 4;
  int lp = t & 63, lr = t >> 6;
  __shared__ float As[16][64], Bs[16][64];
  float acc[4][4] = {};
  for (int k0 = 0; k0 < 256; k0 += 16){
    __syncthreads();
    #pragma unroll
    for (int j = 0; j < 4; ++j){
      int kk = lr + j * 4;
      As[kk][lp] = A[(size_t)(k0 + kk) * 1024 + pi * 64 + lp];
      Bs[kk][lp] = B[(size_t)(k0 + kk) * 1024 + qi * 64 + lp];
    }
    __syncthreads();
    #pragma unroll
    for (int kk = 0; kk < 16; ++kk){
      float4 av = *(const float4*)&As[kk][ty * 4];
      float4 bv = *(const float4*)&Bs[kk][tx * 4];
      float a4[4] = {av.x, av.y, av.z, av.w};
      float b4[4] = {bv.x, bv.y, bv.z, bv.w};
      #pragma unroll
      for (int i = 0; i < 4; ++i)
        #pragma unroll
        for (int j = 0; j < 4; ++j)
          acc[i][j] = fmaf(a4[i], b4[j], acc[i][j]);
    }
  }
  #pragma unroll
  for (int i = 0; i < 4; ++i){
    float4 v = make_float4(acc[i][0], acc[i][1], acc[i][2], acc[i][3]);
    *(float4*)&C[(size_t)(pi * 64 + ty * 4 + i) * 1024 + qi * 64 + tx * 4] = v;
  }
}

// ---------------- composed 5^4 conv + bias; block = (b, l0, d0, h-strip of 8) ----------------
__global__ __launch_bounds__(256) void conv_k(float* __restrict__ ws){
  __shared__ float saff[5 * 5 * AFF_H * AFF_W];  // 11400 f = 45.6 KB (overlay-reused for reduction)
  __shared__ float sK[625];
  int bid0 = blockIdx.x;
  int bid = (bid0 & 7) * 1024 + (bid0 >> 3);     // XCD swizzle (8192 % 8 == 0, bijective)
  int hq = bid & 3, d0 = (bid >> 2) & 31, l0 = (bid >> 7) & 31, b = bid >> 12;
  int h0 = hq * 8;
  int t = threadIdx.x;
  const float* aff = ws + 1048576u + (size_t)b * 1048576;
  float* xc = ws + 3145728u + (size_t)b * 1048576;
  const float* Ktab = ws + 5242880u;
  const float* bias = ws + 5293505u;
  int cl = (l0 == 0) ? 0 : (l0 == 31) ? 2 : 1;
  int cd = (d0 == 0) ? 0 : (d0 == 31) ? 2 : 1;
  int cmain = ((cl * 3 + cd) * 3 + 1) * 3 + 1;
  for (int i = t; i < 625; i += 256) sK[i] = Ktab[cmain * 625 + i];
  // stage aff tile (incremental index tracking: no div/mod in the loop)
  {
    int wi = t % AFF_W;
    int r0 = t / AFF_W;          // <= 6, so hi = r0, plane = 0
    int hi = r0, dd = 0, dl = 0;
    for (int idx = t; idx < 5 * 5 * AFF_H * AFF_W; idx += 256){
      int lp = l0 + dl - 2, dp = d0 + dd - 2, hp = h0 + hi - 2, wp = wi - 2;
      float v = 0.f;
      if ((unsigned)lp < 32u && (unsigned)dp < 32u && (unsigned)hp < 32u && (unsigned)wp < 32u)
        v = aff[(size_t)(lp * 32 + dp) * 1024 + hp * 32 + wp];
      saff[idx] = v;
      wi += 256 - 6 * AFF_W;     // 256 = 6*38 + 28
      int dr = 6;
      if (wi >= AFF_W){ wi -= AFF_W; dr = 7; }
      hi += dr;
      if (hi >= AFF_H){ hi -= AFF_H; dd += 1; if (dd == 5){ dd = 0; dl += 1; } }
    }
  }
  __syncthreads();
  // main pass: 32 units (8 h x 4 w-octets), 8 groups split 125 (plane,dh) row-items
  int u = t & 31, g = t >> 5;
  int hh = u >> 2, oct = u & 3, w0 = oct * 8;
  float acc[8] = {};
  {
    int pl = (g >= 5) ? 1 : 0;
    int dh = g - 5 * pl;
    for (int item = g; item < 125; item += 8){
      float kv[5];
      #pragma unroll
      for (int i = 0; i < 5; ++i) kv[i] = sK[pl * 25 + dh * 5 + i];
      const float* rowp = &saff[(pl * AFF_H + hh + dh) * AFF_W + w0];
      float f[12];
      #pragma unroll
      for (int i = 0; i < 6; ++i){
        float2 v2 = *(const float2*)&rowp[i * 2];
        f[2 * i] = v2.x; f[2 * i + 1] = v2.y;
      }
      #pragma unroll
      for (int dw = 0; dw < 5; ++dw)
        #pragma unroll
        for (int j = 0; j < 8; ++j)
          acc[j] = fmaf(kv[dw], f[j + dw], acc[j]);
      pl += 1; dh += 3;               // advance (pl,dh) by 8 row-items
      if (dh >= 5){ dh -= 5; pl += 1; }
    }
  }
  // shell pass (parallel): h/w-boundary outputs, 8 threads per output, <=2 rounds
  {
    int NS = (hq == 0 || hq == 3) ? 46 : 16;
    int sub = t & 7;
    #pragma unroll
    for (int ro = 0; ro < 2; ++ro){
      int o = ro * 32 + (t >> 3);
      if (o < NS){
        int hs, wx;
        if (h0 == 0){
          if (o < 32){ hs = 0; wx = o; }
          else { int j = o - 32; hs = 1 + (j >> 1); wx = (j & 1) ? 31 : 0; }
        } else if (h0 == 24){
          if (o < 32){ hs = 31; wx = o; }
          else { int j = o - 32; hs = 24 + (j >> 1); wx = (j & 1) ? 31 : 0; }
        } else {
          hs = h0 + (o >> 1); wx = (o & 1) ? 31 : 0;
        }
        int chh = (hs == 0) ? 0 : (hs == 31) ? 2 : 1;
        int cww = (wx == 0) ? 0 : (wx == 31) ? 2 : 1;
        const float* kr = Ktab + (size_t)(((cl * 3 + cd) * 3 + chh) * 3 + cww) * 625;
        float s = 0.f;
        for (int pr = sub; pr < 25; pr += 8){
          const float* kp = kr + pr * 25;
          const float* base = &saff[(pr * AFF_H + (hs - h0)) * AFF_W + wx];
          #pragma unroll
          for (int rh = 0; rh < 5; ++rh)
            #pragma unroll
            for (int rw = 0; rw < 5; ++rw)
              s = fmaf(kp[rh * 5 + rw], base[rh * AFF_W + rw], s);
        }
        s += __shfl_xor(s, 1);
        s += __shfl_xor(s, 2);
        s += __shfl_xor(s, 4);
        if (sub == 0){
          s += bias[l0 * 27 + cd * 9 + chh * 3 + cww];
          xc[(size_t)(l0 * 32 + d0) * 1024 + hs * 32 + wx] = s;
        }
      }
    }
  }
  __syncthreads();
  // reduce the 8 partial groups (overlay into saff), add bias, write interior
  #pragma unroll
  for (int j = 0; j < 8; ++j) saff[(g * 32 + u) * 8 + j] = acc[j];
  __syncthreads();
  {
    int u2 = t >> 3, j = t & 7;
    float s = 0.f;
    #pragma unroll
    for (int gg = 0; gg < 8; ++gg) s += saff[(gg * 32 + u2) * 8 + j];
    int h = h0 + (u2 >> 2);
    int w = (u2 & 3) * 8 + j;
    if (!(h == 0 || h == 31 || w == 0 || w == 31)){
      s += bias[l0 * 27 + cd * 9 + 4];   // interior h,w class (1,1)
      xc[(size_t)(l0 * 32 + d0) * 1024 + h * 32 + w] = s;
    }
  }
}

// ---------------- valp: top3 over q for each (b,p); wave per row ----------------
__global__ __launch_bounds__(256) void topp_k(const float* __restrict__ ws, float* __restrict__ out){
  const float* xc = ws + 3145728u;
  int wid = blockIdx.x * 4 + (threadIdx.x >> 6);
  int lane = threadIdx.x & 63;
  int b = wid >> 10, p = wid & 1023;
  const float* row = xc + (size_t)b * 1048576 + (size_t)p * 1024;
  float a0 = -3.4e38f, a1 = a0, a2 = a0;
  #pragma unroll 4
  for (int j = 0; j < 16; ++j) ins3(a0, a1, a2, row[lane + j * 64]);
  for (int off = 32; off; off >>= 1){
    float b0 = __shfl_xor(a0, off), b1 = __shfl_xor(a1, off), b2 = __shfl_xor(a2, off);
    ins3(a0, a1, a2, b0); ins3(a0, a1, a2, b1); ins3(a0, a1, a2, b2);
  }
  if (lane < 3){
    float v = (lane == 0) ? a0 : (lane == 1) ? a1 : a2;
    out[b * 3072 + lane * 1024 + p] = v;
  }
}

// ---------------- valq: top3 over p for each (b,q); 2-stage coalesced ----------------
__global__ __launch_bounds__(256) void topq1_k(float* __restrict__ ws){
  const float* xc = ws + 3145728u;
  float* part = ws + 5294592u;
  int bid = blockIdx.x;                       // 64: b(2) x pc(8) x qq(4)
  int qq = bid & 3, pc = (bid >> 2) & 7, b = bid >> 5;
  int q = qq * 256 + threadIdx.x;
  const float* base = xc + (size_t)b * 1048576 + q;
  float a0 = -3.4e38f, a1 = a0, a2 = a0;
  #pragma unroll 4
  for (int i = 0; i < 128; ++i) ins3(a0, a1, a2, base[(size_t)(pc * 128 + i) * 1024]);
  part[(size_t)((b * 8 + pc) * 3 + 0) * 1024 + q] = a0;
  part[(size_t)((b * 8 + pc) * 3 + 1) * 1024 + q] = a1;
  part[(size_t)((b * 8 + pc) * 3 + 2) * 1024 + q] = a2;
}

__global__ __launch_bounds__(256) void topq2_k(const float* __restrict__ ws, float* __restrict__ out){
  const float* part = ws + 5294592u;
  int gid = blockIdx.x * 256 + threadIdx.x;   // 2048
  int b = gid >> 10, q = gid & 1023;
  float a0 = -3.4e38f, a1 = a0, a2 = a0;
  #pragma unroll
  for (int c = 0; c < 24; ++c) ins3(a0, a1, a2, part[(size_t)(b * 24 + c) * 1024 + q]);
  out[6144 + b * 3072 + q] = a0;
  out[6144 + b * 3072 + 1024 + q] = a1;
  out[6144 + b * 3072 + 2048 + q] = a2;
}

extern "C" void kernel_launch(void* const* d_in, const int* in_sizes, int n_in,
                              void* d_out, int out_size, void* d_ws, size_t ws_size,
                              hipStream_t stream){
  const float* xp = (const float*)d_in[0];
  const float* xq = (const float*)d_in[1];
  const float* W1 = (const float*)d_in[2];
  const float* B1 = (const float*)d_in[3];
  const float* W2 = (const float*)d_in[4];
  const float* B2 = (const float*)d_in[5];
  float* out = (float*)d_out;
  float* ws = (float*)d_ws;
  hipLaunchKernelGGL(nrm_k,   dim3(64),   dim3(256), 0, stream, xp, xq, ws);
  hipLaunchKernelGGL(tab_k,   dim3(202),  dim3(256), 0, stream, W1, B1, W2, B2, ws);
  hipLaunchKernelGGL(gemm_k,  dim3(512),  dim3(256), 0, stream, ws);
  hipLaunchKernelGGL(conv_k,  dim3(8192), dim3(256), 0, stream, ws);
  hipLaunchKernelGGL(topp_k,  dim3(512),  dim3(256), 0, stream, ws, out);
  hipLaunchKernelGGL(topq1_k, dim3(64),   dim3(256), 0, stream, ws);
  hipLaunchKernelGGL(topq2_k, dim3(8),    dim3(256), 0, stream, ws, out);
}

// Round 3
// 288.793 us; speedup vs baseline: 1.7352x; 1.3460x over previous
//
#include <hip/hip_runtime.h>

// ---------------- workspace layout (float offsets) ----------------
#define AFF_OFF   0u         // [2][1024 p][1024 q]
#define XC_OFF    2097152u   // [2][1024 p][1024 q]
#define K8_OFF    4194304u   // Ktab8 [81 cls][125 item][8] (pad cols 5..7 = 0)
#define BIAS_OFF  4275328u   // [32 l][3 cd][3 ch][3 cw]
#define PART_OFF  4276224u   // topq partials [2][32][3][1024]
#define INV_OFF   4472832u   // inv norms [2 which][2 b][1024]
#define ZP_OFF    4476928u   // zero page (1024 floats)
// total 4477952 floats = 17.9 MB

static __device__ __forceinline__ int imax(int a, int b){ return a > b ? a : b; }
static __device__ __forceinline__ int imin(int a, int b){ return a < b ? a : b; }

static __device__ __forceinline__ void ins3(float& a0, float& a1, float& a2, float v){
  if (v > a0){ a2 = a1; a1 = a0; a0 = v; }
  else if (v > a1){ a2 = a1; a1 = v; }
  else if (v > a2){ a2 = v; }
}

#define GLL4(gsrc, ldst) __builtin_amdgcn_global_load_lds( \
    (const __attribute__((address_space(1))) void*)(gsrc), \
    (__attribute__((address_space(3))) void*)(ldst), 4, 0, 0)

// ---------------- norms only: inv[which][b][p] = 1/max(||x[:,p]||,1e-12) ----------------
__global__ __launch_bounds__(256) void norm_k(const float* __restrict__ xp,
                                              const float* __restrict__ xq,
                                              float* __restrict__ ws){
  int bid = blockIdx.x;                 // 256: which(2) x b(2) x pg(64)
  int pg = bid & 63, b = (bid >> 6) & 1, which = bid >> 7;
  const float* src = (which ? xq : xp) + (size_t)b * 262144;
  int t = threadIdx.x, col = t & 15, cg = t >> 4;
  int p = pg * 16 + col;
  float s = 0.f;
  #pragma unroll
  for (int i = 0; i < 16; ++i){
    float v = src[(size_t)(cg * 16 + i) * 1024 + p];
    s = fmaf(v, v, s);
  }
  __shared__ float red[16][17];
  red[cg][col] = s;
  __syncthreads();
  if (t < 16){
    float tot = 0.f;
    #pragma unroll
    for (int g = 0; g < 16; ++g) tot += red[g][t];
    ws[INV_OFF + (size_t)(which * 2 + b) * 1024 + pg * 16 + t] =
        1.0f / fmaxf(sqrtf(tot), 1e-12f);
  }
}

// ---------------- precompute composed class kernels (padded), bias, zero page ----------------
__global__ __launch_bounds__(256) void tab_k(const float* __restrict__ W1,
                                             const float* __restrict__ B1,
                                             const float* __restrict__ W2,
                                             const float* __restrict__ B2,
                                             float* __restrict__ ws){
  __shared__ float sW1[1296], sW2[1296];
  for (int i = threadIdx.x; i < 1296; i += 256){ sW1[i] = W1[i]; sW2[i] = W2[i]; }
  __syncthreads();
  int tid = blockIdx.x * 256 + threadIdx.x;
  if (tid < 50625){
    int c = tid / 625, r = tid % 625;
    int cw = c % 3, ch = (c / 3) % 3, cd = (c / 9) % 3, cl = c / 27;
    int rw = r % 5, rh = (r / 5) % 5, rd = (r / 25) % 5, rl = r / 125;
    int al0 = imax(0, rl - 2), al1 = imin(2, rl);
    if (cl == 0) al0 = imax(al0, 1);
    if (cl == 2) al1 = imin(al1, 1);
    int ad0 = imax(0, rd - 2), ad1 = imin(2, rd);
    if (cd == 0) ad0 = imax(ad0, 1);
    if (cd == 2) ad1 = imin(ad1, 1);
    int ah0 = imax(0, rh - 2), ah1 = imin(2, rh);
    if (ch == 0) ah0 = imax(ah0, 1);
    if (ch == 2) ah1 = imin(ah1, 1);
    int aw0 = imax(0, rw - 2), aw1 = imin(2, rw);
    if (cw == 0) aw0 = imax(aw0, 1);
    if (cw == 2) aw1 = imin(aw1, 1);
    float s = 0.f;
    for (int a = al0; a <= al1; ++a)
      for (int bq = ad0; bq <= ad1; ++bq)
        for (int cq = ah0; cq <= ah1; ++cq)
          for (int dq = aw0; dq <= aw1; ++dq){
            int q2 = ((a * 3 + bq) * 3 + cq) * 3 + dq;
            int q1 = (((rl - a) * 3 + (rd - bq)) * 3 + (rh - cq)) * 3 + (rw - dq);
            for (int co = 0; co < 16; ++co)
              s += sW2[co * 81 + q2] * sW1[co * 81 + q1];
          }
    int item = (r * 205) >> 10;           // r/5
    int j = r - item * 5;
    ws[K8_OFF + (size_t)c * 1000 + item * 8 + j] = s;
  } else if (tid < 51489){
    int t2 = tid - 50625;
    int l = t2 / 27, rest = t2 % 27;
    int cd = rest / 9, ch = (rest / 3) % 3, cw = rest % 3;
    float v = 0.f;
    for (int i = 0; i < 3; ++i){ int y = l + i - 1; if (y >= 0 && y < 32) v += B2[i]; }
    int jlo = (cd == 0) ? 1 : 0, jhi = (cd == 2) ? 1 : 2;
    int klo = (ch == 0) ? 1 : 0, khi = (ch == 2) ? 1 : 2;
    int mlo = (cw == 0) ? 1 : 0, mhi = (cw == 2) ? 1 : 2;
    for (int i = 0; i < 3; ++i){
      int y = l + i - 1; if (y < 0 || y >= 32) continue;
      for (int co = 0; co < 16; ++co){
        float b1e = 0.f;
        for (int i2 = 0; i2 < 3; ++i2){
          int y2 = y + i2 - 1; if (y2 >= 0 && y2 < 32) b1e += B1[i2 * 16 + co];
        }
        float S = 0.f;
        for (int j = jlo; j <= jhi; ++j)
          for (int k = klo; k <= khi; ++k)
            for (int m = mlo; m <= mhi; ++m)
              S += sW2[co * 81 + ((i * 3 + j) * 3 + k) * 3 + m];
        v += b1e * S;
      }
    }
    ws[BIAS_OFF + t2] = v;
  } else if (tid < 52513){
    ws[ZP_OFF + (tid - 51489)] = 0.f;                 // zero page
  } else if (tid < 82888){
    int u = tid - 52513;                              // pad cols 5..7 of Ktab8
    int c = u / 375, r2 = u % 375;
    int item = r2 / 3, j = 5 + r2 % 3;
    ws[K8_OFF + (size_t)c * 1000 + item * 8 + j] = 0.f;
  }
}

// ---------------- aff = (xp^T xq) scaled by inv norms; per batch 1024x1024, K=256 ----------------
__global__ __launch_bounds__(256) void gemm_k(const float* __restrict__ xp,
                                              const float* __restrict__ xq,
                                              float* __restrict__ ws){
  int bid = blockIdx.x;                       // 512: b(2) x pi(16) x qi(16)
  int qi = bid & 15, pi = (bid >> 4) & 15, b = bid >> 8;
  const float* A = xp + (size_t)b * 262144;   // [c][p]
  const float* B = xq + (size_t)b * 262144;   // [c][q]
  float* C = ws + AFF_OFF + (size_t)b * 1048576;
  const float* invp = ws + INV_OFF + (size_t)b * 1024;
  const float* invq = ws + INV_OFF + 2048u + (size_t)b * 1024;
  int t = threadIdx.x, tx = t & 15, ty = t >> 4;
  int lp = t & 63, lr = t >> 6;
  __shared__ float As[16][64], Bs[16][64];
  float acc[4][4] = {};
  for (int k0 = 0; k0 < 256; k0 += 16){
    __syncthreads();
    #pragma unroll
    for (int j = 0; j < 4; ++j){
      int kk = lr + j * 4;
      As[kk][lp] = A[(size_t)(k0 + kk) * 1024 + pi * 64 + lp];
      Bs[kk][lp] = B[(size_t)(k0 + kk) * 1024 + qi * 64 + lp];
    }
    __syncthreads();
    #pragma unroll
    for (int kk = 0; kk < 16; ++kk){
      float4 av = *(const float4*)&As[kk][ty * 4];
      float4 bv = *(const float4*)&Bs[kk][tx * 4];
      float a4[4] = {av.x, av.y, av.z, av.w};
      float b4[4] = {bv.x, bv.y, bv.z, bv.w};
      #pragma unroll
      for (int i = 0; i < 4; ++i)
        #pragma unroll
        for (int j = 0; j < 4; ++j)
          acc[i][j] = fmaf(a4[i], b4[j], acc[i][j]);
    }
  }
  float iva[4], ivb[4];
  #pragma unroll
  for (int i = 0; i < 4; ++i){
    iva[i] = invp[pi * 64 + ty * 4 + i];
    ivb[i] = invq[qi * 64 + tx * 4 + i];
  }
  #pragma unroll
  for (int i = 0; i < 4; ++i){
    float4 v = make_float4(acc[i][0] * iva[i] * ivb[0], acc[i][1] * iva[i] * ivb[1],
                           acc[i][2] * iva[i] * ivb[2], acc[i][3] * iva[i] * ivb[3]);
    *(float4*)&C[(size_t)(pi * 64 + ty * 4 + i) * 1024 + qi * 64 + tx * 4] = v;
  }
}

// ---------------- composed 5^4 conv, d-streamed; block = (b, l0, hq, dq) ----------------
// LDS: 5 rolling planes [5 dl][12 hi][36 wi] + 2 kernel tables [125][8]
__global__ __launch_bounds__(256, 3) void conv_k(float* __restrict__ ws){
  __shared__ __align__(16) float lds[12800];      // 5*2160 + 2000 = 51200 B
  float* slots = lds;
  float* kvA = lds + 10800;

  int bid0 = blockIdx.x;
  int bid = (bid0 & 7) * 128 + (bid0 >> 3);       // XCD swizzle (1024 % 8 == 0)
  int dq = bid & 3, hq = (bid >> 2) & 3, l0 = (bid >> 4) & 31, b = bid >> 9;
  int h0 = hq * 8, dstart = dq * 8;
  int t = threadIdx.x;
  const float* affB = ws + AFF_OFF + (size_t)b * 1048576;
  float* xc = ws + XC_OFF + (size_t)b * 1048576;
  const float* K8G = ws + K8_OFF;
  const float* bias = ws + BIAS_OFF;
  const float* zp = ws + ZP_OFF;

  int cl = (l0 == 0) ? 0 : (l0 == 31) ? 2 : 1;
  int chB = (hq == 0) ? 0 : (hq == 3) ? 2 : 1;    // boundary-row h class (if any)

  // A-phase lane constants: lane = slice(3b) | hsel(1b) | oct(2b)
  int wv = t >> 6, u3 = t & 7;
  int oct = u3 & 3, hl = wv * 2 + (u3 >> 2);      // output row within strip, 0..7
  int hA = h0 + hl;
  int chA = (hA == 0) ? 0 : (hA == 31) ? 2 : 1;
  const float* kvb = ((hq == 0 && hl == 0) || (hq == 3 && hl == 7)) ? kvA : (kvA + 1000);
  int sl = (t >> 3) & 7;

  // B-phase lane constants: 16 outputs (8 h x w in {0,31}) x 16 sub-lanes
  int outB = t >> 4, subB = t & 15;
  int hlB = outB >> 1, wx31 = outB & 1;
  int hB = h0 + hlB;
  int chB2 = (hB == 0) ? 0 : (hB == 31) ? 2 : 1;
  int cwB = wx31 ? 2 : 0;
  int wofB = wx31 ? 28 : 0;

  // staging offsets (9 rounds of 256 lanes covering 2160 floats/plane)
  int o0, o1, o2, o3, o4, o5, o6, o7, o8;
#define PRE(r) { int flat = (r)*256 + t; \
    int wi = flat % 36; int rest = flat / 36; int hi = rest % 12; int dl2 = rest / 12; \
    int lp_ = l0 + dl2 - 2, hp_ = h0 + hi - 2, wp_ = wi - 2; \
    bool ok = ((unsigned)lp_ < 32u) && ((unsigned)hp_ < 32u) && ((unsigned)wp_ < 32u); \
    o##r = ok ? (lp_ * 32768 + hp_ * 32 + wp_) : -1; }
  PRE(0) PRE(1) PRE(2) PRE(3) PRE(4) PRE(5) PRE(6) PRE(7) PRE(8)
#undef PRE

#define STG(r, sp_) { const float* s_ = (pOK_ && o##r >= 0) ? (affB + o##r + dpo_) : zp; \
    GLL4(s_, sp_ + (r)*256 + t); }
#define STAGE(si_, dpv_) do { \
    int dp_ = (dpv_); bool pOK_ = ((unsigned)dp_ < 32u); int dpo_ = dp_ * 1024; \
    float* sp_ = slots + (si_) * 2160; \
    STG(0, sp_) STG(1, sp_) STG(2, sp_) STG(3, sp_) \
    STG(4, sp_) STG(5, sp_) STG(6, sp_) STG(7, sp_) \
    if (t < 112) sp_[2048 + t] = (pOK_ && o8 >= 0) ? affB[o8 + dpo_] : 0.f; \
  } while (0)

#define LKV(r, k0_, k1_) { int ii_ = (r)*256 + t; \
    const float* s_ = (ii_ < 1000) ? (k0_ + ii_) : (k1_ + (ii_ - 1000)); \
    GLL4(s_, kvA + ii_); }
#define LOADKV(cdv_) do { int cd_ = (cdv_); \
    const float* k0_ = K8G + (size_t)((((cl*3+cd_)*3+chB)*3)+1) * 1000; \
    const float* k1_ = K8G + (size_t)((((cl*3+cd_)*3+1)*3)+1) * 1000; \
    LKV(0,k0_,k1_) LKV(1,k0_,k1_) LKV(2,k0_,k1_) LKV(3,k0_,k1_) \
    LKV(4,k0_,k1_) LKV(5,k0_,k1_) LKV(6,k0_,k1_) \
    if (t < 208) kvA[1792 + t] = k1_[792 + t]; \
  } while (0)

  int cdCur = (dstart == 0) ? 0 : 1;
  LOADKV(cdCur);
  STAGE((dstart + 8)  % 5, dstart - 2);
  STAGE((dstart + 9)  % 5, dstart - 1);
  STAGE((dstart + 10) % 5, dstart);
  STAGE((dstart + 11) % 5, dstart + 1);
  STAGE((dstart + 12) % 5, dstart + 2);
  asm volatile("s_waitcnt vmcnt(0)" ::: "memory");
  __syncthreads();

  for (int s8 = 0; s8 < 8; ++s8){
    int d = dstart + s8;
    int cd = (d == 0) ? 0 : (d == 31) ? 2 : 1;
    if (cd != cdCur){                    // rare: once per block at most
      LOADKV(cd); cdCur = cd;
      asm volatile("s_waitcnt vmcnt(0)" ::: "memory");
      __syncthreads();
    }
    int scomp = (d + 3) % 5;

    // ---- main row pass (w 1..30 via sliding window; boundary-h class via kvb) ----
    float acc[8] = {0.f, 0.f, 0.f, 0.f, 0.f, 0.f, 0.f, 0.f};
    {
      int idx = sl;
      int pl0 = (sl >= 5) ? 1 : 0;
      int dh = sl - 5 * pl0;
      int dd = pl0, dl = 0;
      while (idx < 125){
        int si = scomp + dd; if (si >= 5) si -= 5;
        int row = dl * 12 + hl + dh;
        const float4* rp4 = (const float4*)(slots + si * 2160 + row * 36 + oct * 8);
        float4 fa = rp4[0], fb = rp4[1], fc = rp4[2];
        const float* kp = kvb + idx * 8;
        float4 kq = *(const float4*)kp;
        float k4 = kp[4];
        float f[12] = {fa.x, fa.y, fa.z, fa.w, fb.x, fb.y, fb.z, fb.w,
                       fc.x, fc.y, fc.z, fc.w};
        float kv5[5] = {kq.x, kq.y, kq.z, kq.w, k4};
        #pragma unroll
        for (int dw = 0; dw < 5; ++dw)
          #pragma unroll
          for (int j = 0; j < 8; ++j)
            acc[j] = fmaf(kv5[dw], f[j + dw], acc[j]);
        idx += 8;
        dh += 3; dd += 1;
        if (dh >= 5){ dh -= 5; dd += 1; }
        if (dd >= 5){ dd -= 5; dl += 1; }
      }
    }
    #pragma unroll
    for (int j = 0; j < 8; ++j) acc[j] += __shfl_xor(acc[j], 8);
    #pragma unroll
    for (int j = 0; j < 8; ++j) acc[j] += __shfl_xor(acc[j], 16);
    #pragma unroll
    for (int j = 0; j < 8; ++j) acc[j] += __shfl_xor(acc[j], 32);
    if ((t & 56) == 0){
      float bv = bias[l0 * 27 + cd * 9 + chA * 3 + 1];
      float v[8];
      #pragma unroll
      for (int j = 0; j < 8; ++j) v[j] = acc[j] + bv;
      float* orow = xc + (size_t)(l0 * 32 + d) * 1024 + hA * 32 + oct * 8;
      if (oct == 0){
        orow[1] = v[1];
        *(float2*)&orow[2] = make_float2(v[2], v[3]);
        *(float4*)&orow[4] = make_float4(v[4], v[5], v[6], v[7]);
      } else if (oct == 3){
        *(float4*)&orow[0] = make_float4(v[0], v[1], v[2], v[3]);
        *(float2*)&orow[4] = make_float2(v[4], v[5]);
        orow[6] = v[6];
      } else {
        *(float4*)&orow[0] = make_float4(v[0], v[1], v[2], v[3]);
        *(float4*)&orow[4] = make_float4(v[4], v[5], v[6], v[7]);
      }
    }

    // ---- w-boundary column pass (16 outputs, exact per-output class incl corners) ----
    {
      float accB = 0.f;
      const float* kgB = K8G + (size_t)((((cl*3+cd)*3+chB2)*3) + cwB) * 1000;
      for (int idx = subB; idx < 125; idx += 16){
        int pl = (idx * 205) >> 10;       // idx/5
        int rh = idx - pl * 5;
        int dl = (pl * 205) >> 10;        // pl/5
        int dd = pl - dl * 5;
        int si = scomp + dd; if (si >= 5) si -= 5;
        int row = dl * 12 + hlB + rh;
        const float4* rp4 = (const float4*)(slots + si * 2160 + row * 36 + wofB);
        float4 q1 = rp4[0], q2 = rp4[1];
        const float* ka = kgB + idx * 8;
        float4 kq = *(const float4*)ka;
        float k4 = ka[4];
        float e0 = wx31 ? q1.w : q1.x;
        float e1 = wx31 ? q2.x : q1.y;
        float e2 = wx31 ? q2.y : q1.z;
        float e3 = wx31 ? q2.z : q1.w;
        float e4 = wx31 ? q2.w : q2.x;
        accB = fmaf(kq.x, e0, accB);
        accB = fmaf(kq.y, e1, accB);
        accB = fmaf(kq.z, e2, accB);
        accB = fmaf(kq.w, e3, accB);
        accB = fmaf(k4,  e4, accB);
      }
      accB += __shfl_xor(accB, 1);
      accB += __shfl_xor(accB, 2);
      accB += __shfl_xor(accB, 4);
      accB += __shfl_xor(accB, 8);
      if (subB == 0){
        float bv = bias[l0 * 27 + cd * 9 + chB2 * 3 + cwB];
        xc[(size_t)(l0 * 32 + d) * 1024 + hB * 32 + (wx31 ? 31 : 0)] = accB + bv;
      }
    }

    __syncthreads();                        // all reads of recycled slot done
    if (s8 < 7) STAGE((d + 13) % 5, d + 3); // bring in plane d+3
    asm volatile("s_waitcnt vmcnt(0)" ::: "memory");
    __syncthreads();
  }
#undef STG
#undef STAGE
#undef LKV
#undef LOADKV
}

// ---------------- valp: top3 over q for each (b,p); wave per row, float4 ----------------
__global__ __launch_bounds__(256) void topp_k(const float* __restrict__ ws, float* __restrict__ out){
  const float* xc = ws + XC_OFF;
  int wid = blockIdx.x * 4 + (threadIdx.x >> 6);
  int lane = threadIdx.x & 63;
  int b = wid >> 10, p = wid & 1023;
  const float4* row4 = (const float4*)(xc + (size_t)b * 1048576 + (size_t)p * 1024);
  float a0 = -3.4e38f, a1 = a0, a2 = a0;
  #pragma unroll
  for (int j = 0; j < 4; ++j){
    float4 v = row4[j * 64 + lane];
    ins3(a0, a1, a2, v.x); ins3(a0, a1, a2, v.y);
    ins3(a0, a1, a2, v.z); ins3(a0, a1, a2, v.w);
  }
  for (int off = 32; off; off >>= 1){
    float b0 = __shfl_xor(a0, off), b1 = __shfl_xor(a1, off), b2 = __shfl_xor(a2, off);
    ins3(a0, a1, a2, b0); ins3(a0, a1, a2, b1); ins3(a0, a1, a2, b2);
  }
  if (lane < 3){
    float v = (lane == 0) ? a0 : (lane == 1) ? a1 : a2;
    out[b * 3072 + lane * 1024 + p] = v;
  }
}

// ---------------- valq: top3 over p for each (b,q); 2-stage coalesced ----------------
__global__ __launch_bounds__(256) void topq1_k(float* __restrict__ ws){
  const float* xc = ws + XC_OFF;
  float* part = ws + PART_OFF;
  int bid = blockIdx.x;                       // 256: b(2) x pc(32) x qq(4)
  int qq = bid & 3, pc = (bid >> 2) & 31, b = bid >> 7;
  int q = qq * 256 + threadIdx.x;
  const float* base = xc + (size_t)b * 1048576 + q;
  float a0 = -3.4e38f, a1 = a0, a2 = a0;
  #pragma unroll 4
  for (int i = 0; i < 32; ++i) ins3(a0, a1, a2, base[(size_t)(pc * 32 + i) * 1024]);
  part[(size_t)((b * 32 + pc) * 3 + 0) * 1024 + q] = a0;
  part[(size_t)((b * 32 + pc) * 3 + 1) * 1024 + q] = a1;
  part[(size_t)((b * 32 + pc) * 3 + 2) * 1024 + q] = a2;
}

__global__ __launch_bounds__(256) void topq2_k(const float* __restrict__ ws, float* __restrict__ out){
  const float* part = ws + PART_OFF;
  int gid = blockIdx.x * 256 + threadIdx.x;   // 2048
  int b = gid >> 10, q = gid & 1023;
  float a0 = -3.4e38f, a1 = a0, a2 = a0;
  #pragma unroll 4
  for (int c = 0; c < 96; ++c) ins3(a0, a1, a2, part[(size_t)(b * 96 + c) * 1024 + q]);
  out[6144 + b * 3072 + q] = a0;
  out[6144 + b * 3072 + 1024 + q] = a1;
  out[6144 + b * 3072 + 2048 + q] = a2;
}

extern "C" void kernel_launch(void* const* d_in, const int* in_sizes, int n_in,
                              void* d_out, int out_size, void* d_ws, size_t ws_size,
                              hipStream_t stream){
  const float* xp = (const float*)d_in[0];
  const float* xq = (const float*)d_in[1];
  const float* W1 = (const float*)d_in[2];
  const float* B1 = (const float*)d_in[3];
  const float* W2 = (const float*)d_in[4];
  const float* B2 = (const float*)d_in[5];
  float* out = (float*)d_out;
  float* ws = (float*)d_ws;
  hipLaunchKernelGGL(norm_k,  dim3(256),  dim3(256), 0, stream, xp, xq, ws);
  hipLaunchKernelGGL(tab_k,   dim3(324),  dim3(256), 0, stream, W1, B1, W2, B2, ws);
  hipLaunchKernelGGL(gemm_k,  dim3(512),  dim3(256), 0, stream, xp, xq, ws);
  hipLaunchKernelGGL(conv_k,  dim3(1024), dim3(256), 0, stream, ws);
  hipLaunchKernelGGL(topp_k,  dim3(512),  dim3(256), 0, stream, ws, out);
  hipLaunchKernelGGL(topq1_k, dim3(256),  dim3(256), 0, stream, ws);
  hipLaunchKernelGGL(topq2_k, dim3(8),    dim3(256), 0, stream, ws, out);
}